// Round 3
// baseline (17046.016 us; speedup 1.0000x reference)
//
#include <hip/hip_runtime.h>
#include <math.h>

#define B_ 16
#define T_ 512
#define E_ 2048
#define H_ 1024
#define D_ 128
#define G_TOTAL 256          // 256 blocks = 1/CU; blocks %8==0 scan (one XCD), rest GEMM
#define NSCAN 32             // scan WGs (32 rows each)
#define N_GEMM (G_TOTAL - NSCAN)   // 224 gemm WGs
#define N_JOBS 2048          // 128 m-tiles x 16 n-tiles
#define FAST_SPINS 10        // bounded sc0 poll attempts before device-scope escalation

typedef unsigned long long u64;
typedef unsigned int u32;
typedef __attribute__((ext_vector_type(4))) u32 v4u;

// ---------------- ws layout ----------------
// [1024, 9216)   : cnt[128] m-tile counters, stride 16 u32 -- zeroed
// [16384,32768)  : hbuf2[2][H_] u64 {tag,val} -- zeroed (h0=0, tag=0)
// [32768,98304)  : hs[B_][H_] float (fully written by scan)
// [131072,+32MB) : xW[B_*T_][H_] float (tile-gated, no zeroing needed)

// ---- device-scope coherent ops (proven baseline transport) ----
__device__ __forceinline__ void store_f32_cohere(float* p, float v) {
    asm volatile("global_store_dword %0, %1, off sc0 sc1" :: "v"(p), "v"(v) : "memory");
}
__device__ __forceinline__ u32 load_u32_cohere(const u32* p) {
    u32 r;
    asm volatile("global_load_dword %0, %1, off sc0 sc1\n\ts_waitcnt vmcnt(0)"
                 : "=v"(r) : "v"(p) : "memory");
    return r;
}

// ---- h publish: dual-scope. sc0 lands in home-XCD L2 (fast consumers);
//      sc0 sc1 reaches the device coherence point (escalated consumers).
//      Same value both times -> any completion order is correct. ----
__device__ __forceinline__ void store_h64_dual(u64* p, u64 v) {
    asm volatile(
        "global_store_dwordx2 %0, %1, off sc0\n\t"
        "global_store_dwordx2 %0, %1, off sc0 sc1"
        :: "v"(p), "v"(v) : "memory");
}

// ---- poll packets: one asm block, internal vmcnt(0) (no cross-asm reg hazard) ----
// fast: sc0 only (bypass L1, hit home L2). xW via sc0 is first-touch-correct:
// the tile gate (device-scope) confirmed the data before any lane ever loads it,
// and stores never allocate lines in the consumer XCD's L2 -> no stale copy.
__device__ __forceinline__ void poll_fast(const u64* ph, const float* pxw,
                                          v4u& A, v4u& B, float& xw) {
    asm volatile(
        "global_load_dwordx4 %0, %3, off sc0\n\t"
        "global_load_dwordx4 %1, %3, off offset:16 sc0\n\t"
        "global_load_dword   %2, %4, off sc0\n\t"
        "s_waitcnt vmcnt(0)"
        : "=&v"(A), "=&v"(B), "=&v"(xw)
        : "v"(ph), "v"(pxw)
        : "memory");
}
// slow: full device scope (exact baseline-proven shape) -- guaranteed to see the
// dual store's sc0 sc1 copy, so escalation always terminates.
__device__ __forceinline__ void poll_dev(const u64* ph, const float* pxw,
                                         v4u& A, v4u& B, float& xw) {
    asm volatile(
        "global_load_dwordx4 %0, %3, off sc0 sc1\n\t"
        "global_load_dwordx4 %1, %3, off offset:16 sc0 sc1\n\t"
        "global_load_dword   %2, %4, off sc0 sc1\n\t"
        "s_waitcnt vmcnt(0)"
        : "=&v"(A), "=&v"(B), "=&v"(xw)
        : "v"(ph), "v"(pxw)
        : "memory");
}

template <int CTRL>
__device__ __forceinline__ float dpp_xadd(float v) {
    int vi = __float_as_int(v);
    int t  = __builtin_amdgcn_update_dpp(vi, vi, CTRL, 0xF, 0xF, true);
    return v + __int_as_float(t);
}

__device__ __forceinline__ float fast_tanh(float x) {
    float ax = fabsf(x);
    float e  = __expf(-2.0f * ax);
    float r  = __fdividef(1.0f - e, 1.0f + e);
    return copysignf(r, x);
}

// ---- one 64x64 GEMM tile job (unchanged from proven baseline) ----
__device__ __forceinline__ void gemm_tile(
    int mt, int nt, int tid,
    const float* __restrict__ x, const float* __restrict__ Wih,
    const float* __restrict__ bih, const float* __restrict__ bhh,
    float* xW, u32* cnt, float (*As)[17], float (*Bs)[17])
{
    const int tx = tid & 15, ty = tid >> 4;
    const int lrow = tid >> 2, lcol = (tid & 3) * 4;
    const float* Ag = x   + (size_t)(mt * 64 + lrow) * E_ + lcol;
    const float* Bg = Wih + (size_t)(nt * 64 + lrow) * E_ + lcol;

    float acc[4][4] = {};
    for (int kt = 0; kt < E_; kt += 16) {
        float4 av = *(const float4*)(Ag + kt);
        float4 bv = *(const float4*)(Bg + kt);
        As[lrow][lcol + 0] = av.x; As[lrow][lcol + 1] = av.y;
        As[lrow][lcol + 2] = av.z; As[lrow][lcol + 3] = av.w;
        Bs[lrow][lcol + 0] = bv.x; Bs[lrow][lcol + 1] = bv.y;
        Bs[lrow][lcol + 2] = bv.z; Bs[lrow][lcol + 3] = bv.w;
        __syncthreads();
#pragma unroll
        for (int kk = 0; kk < 16; ++kk) {
            float a0 = As[ty * 4 + 0][kk], a1 = As[ty * 4 + 1][kk];
            float a2 = As[ty * 4 + 2][kk], a3 = As[ty * 4 + 3][kk];
            float b0 = Bs[tx * 4 + 0][kk], b1 = Bs[tx * 4 + 1][kk];
            float b2 = Bs[tx * 4 + 2][kk], b3 = Bs[tx * 4 + 3][kk];
            acc[0][0] += a0 * b0; acc[0][1] += a0 * b1; acc[0][2] += a0 * b2; acc[0][3] += a0 * b3;
            acc[1][0] += a1 * b0; acc[1][1] += a1 * b1; acc[1][2] += a1 * b2; acc[1][3] += a1 * b3;
            acc[2][0] += a2 * b0; acc[2][1] += a2 * b1; acc[2][2] += a2 * b2; acc[2][3] += a2 * b3;
            acc[3][0] += a3 * b0; acc[3][1] += a3 * b1; acc[3][2] += a3 * b2; acc[3][3] += a3 * b3;
        }
        __syncthreads();
    }
#pragma unroll
    for (int i = 0; i < 4; ++i) {
        const int m = mt * 64 + ty * 4 + i;
#pragma unroll
        for (int j = 0; j < 4; ++j) {
            const int n = nt * 64 + tx * 4 + j;
            store_f32_cohere(xW + (size_t)m * H_ + n, acc[i][j] + bih[n] + bhh[n]);
        }
    }
    asm volatile("s_waitcnt vmcnt(0)" ::: "memory");  // own stores at coherence point
    __syncthreads();                                  // all threads' stores drained
    if (tid == 0) atomicAdd(cnt + mt * 16, 1u);       // device-scope publish
}

// ================= Fused kernel =================
__global__ __launch_bounds__(256, 1) void fused_scan_gemm(
    const float* __restrict__ x, const float* __restrict__ Wih,
    const float* __restrict__ bih, const float* __restrict__ bhh,
    const float* __restrict__ Whh, const int* __restrict__ lengths,
    u32* cnt, u64* hbuf2, float* xW, float* hs)
{
    __shared__ float As[64][17];
    __shared__ float Bs[64][17];
    __shared__ float hsh[2][H_];

    const int tid = threadIdx.x;
    const int wg  = blockIdx.x;

    if ((wg & 7) != 0) {
        // -------- GEMM role: static striping, m-major (tile gate fills in order) ----
        const int gi = wg - (wg >> 3) - 1;           // dense 0..223 over non-scan blocks
        for (int j = gi; j < N_JOBS; j += N_GEMM)
            gemm_tile(j >> 4, j & 15, tid, x, Wih, bih, bhh, xW, cnt, As, Bs);
        return;
    }

    // -------- scan role: slot = wg/8 (32 slots, one XCD under %8 round-robin) ------
    const int slot = wg >> 3;
    const int sub  = tid & 7;                 // lane within row (8 lanes/row)
    const int row  = slot * 32 + (tid >> 3);  // this lane's output row

    // W_hh fragment: wv[j] covers k = 4*sub + 32*j .. +3  (128 VGPRs)
    float4 wv[32];
#pragma unroll
    for (int j = 0; j < 32; ++j)
        wv[j] = *(const float4*)(Whh + (size_t)row * H_ + 4 * sub + 32 * j);

    int s = 0, cur = 0, conf = -1;

    for (int b = 0; b < B_; ++b) {
        const int len = lengths[b];
        for (int t = 0; t < len; ++t) {
            const int m  = b * T_ + t;
            const int mt = m >> 6;
            if (mt > conf) {   // xW tile gate (16 n-jobs done?) -- 128 total gates
                u32 c;
                do { c = load_u32_cohere(cnt + mt * 16); } while (c < 16u);
                conf = mt;
            }

            // ---- consume h slots 4tid..4tid+3 + this step's xW ----
            const u64*   ph  = hbuf2 + (size_t)(s & 1) * H_ + 4 * tid;
            const float* pxw = xW + (size_t)m * H_ + row;
            const u32 want = (u32)s;
            v4u A, Bv; float xw;
            int spin = 0;
            for (;;) {
                poll_fast(ph, pxw, A, Bv, xw);
                if ((A.y == want) & (A.w == want) & (Bv.y == want) & (Bv.w == want))
                    break;
                if (++spin >= FAST_SPINS) {
                    // escalation: device-scope poll (always terminates: dual store)
                    do {
                        __builtin_amdgcn_s_sleep(2);
                        poll_dev(ph, pxw, A, Bv, xw);
                    } while (!((A.y == want) & (A.w == want) &
                               (Bv.y == want) & (Bv.w == want)));
                    break;
                }
            }

            // ---- stage h into LDS (double-buffered) ----
            float4 hv4;
            hv4.x = __uint_as_float(A.x);
            hv4.y = __uint_as_float(A.z);
            hv4.z = __uint_as_float(Bv.x);
            hv4.w = __uint_as_float(Bv.z);
            *(float4*)&hsh[cur][4 * tid] = hv4;
            __syncthreads();

            // ---- matvec: row . h, k = 4*sub + 32*j + c ----
            const float* hrow = &hsh[cur][4 * sub];
            float p0 = 0.f, p1 = 0.f, p2 = 0.f, p3 = 0.f;
#pragma unroll
            for (int j = 0; j < 32; ++j) {
                float4 hv = *(const float4*)(hrow + 32 * j);
                p0 += wv[j].x * hv.x;
                p1 += wv[j].y * hv.y;
                p2 += wv[j].z * hv.z;
                p3 += wv[j].w * hv.w;
            }
            float pr = (p0 + p1) + (p2 + p3);
            pr = dpp_xadd<0xB1>(pr);    // quad xor1
            pr = dpp_xadd<0x4E>(pr);    // quad xor2
            pr = dpp_xadd<0x141>(pr);   // row_half_mirror -> full 8-lane row sum

            const float v = fast_tanh(xw + pr);
            if (sub == 0) {
                u64 pk = ((u64)(u32)(s + 1) << 32) | (u64)__float_as_uint(v);
                store_h64_dual(hbuf2 + (size_t)((s + 1) & 1) * H_ + row, pk);
                if (t == len - 1) hs[(size_t)b * H_ + row] = v;
            }
            cur ^= 1;
            ++s;
        }
    }
}

// ================= out = hs @ W_l1^T + b_l1  (16x128) =================
__global__ __launch_bounds__(128) void out_gemm(
    const float* __restrict__ hs, const float* __restrict__ Wl1,
    const float* __restrict__ bl1, float* __restrict__ out)
{
    __shared__ float hshared[H_];
    const int b = blockIdx.x;
    const int d = threadIdx.x;
    for (int i = d; i < H_ / 4; i += 128)
        ((float4*)hshared)[i] = ((const float4*)(hs + (size_t)b * H_))[i];
    __syncthreads();
    float acc = 0.f;
    const float* wrow = Wl1 + (size_t)d * H_;
    for (int h = 0; h < H_; h += 4) {
        float4 w = *(const float4*)(wrow + h);
        acc += w.x * hshared[h] + w.y * hshared[h + 1]
             + w.z * hshared[h + 2] + w.w * hshared[h + 3];
    }
    out[b * D_ + d] = acc + bl1[d];
}

extern "C" void kernel_launch(void* const* d_in, const int* in_sizes, int n_in,
                              void* d_out, int out_size, void* d_ws, size_t ws_size,
                              hipStream_t stream) {
    const float* x       = (const float*)d_in[0];
    const int*   lengths = (const int*)  d_in[1];
    const float* Wih     = (const float*)d_in[2];
    const float* Whh     = (const float*)d_in[3];
    const float* bih     = (const float*)d_in[4];
    const float* bhh     = (const float*)d_in[5];
    const float* Wl1     = (const float*)d_in[6];
    const float* bl1     = (const float*)d_in[7];
    float* out = (float*)d_out;

    char* ws = (char*)d_ws;
    u32*   cnt   = (u32*)(ws + 1024);     // 128 tiles x 16-u32 stride = 8 KB
    u64*   hbuf2 = (u64*)(ws + 16384);    // 16 KB
    float* hs    = (float*)(ws + 32768);  // 64 KB
    float* xW    = (float*)(ws + 131072); // 32 MB

    // zero cnt + hbuf2 (h0=0, tag 0); ws re-poisoned 0xAA every launch
    hipMemsetAsync(ws, 0, 32768, stream);

    fused_scan_gemm<<<G_TOTAL, 256, 0, stream>>>(
        x, Wih, bih, bhh, Whh, lengths, cnt, hbuf2, xW, hs);

    out_gemm<<<B_, D_, 0, stream>>>(hs, Wl1, bl1, out);
}

// Round 5
// 8588.797 us; speedup vs baseline: 1.9847x; 1.9847x over previous
//
#include <hip/hip_runtime.h>
#include <math.h>

#define B_ 16
#define T_ 512
#define E_ 2048
#define H_ 1024
#define D_ 128
#define G_SCAN 32            // scan WGs (halved vs baseline: poll-contention lever)
#define ROWS_PER_WG 32       // H_/G_SCAN
#define G_TOTAL 256          // scan + gemm WGs, all co-resident (1 block/CU)
#define N_JOBS 2048          // 128 m-tiles x 16 n-tiles
#define TICK_P 40            // pacing gate (inert unless steps < ~400ns)
#define START_DELAY 2000
#define T0_MAGIC 0x7F7F7F7Fu

typedef unsigned long long u64;
typedef unsigned int u32;
typedef __attribute__((ext_vector_type(4))) u32 v4u;

// ---------------- ws layout ----------------
// [256,  264)    : T0 handshake slot (u64 {magic,t0}) -- zeroed each launch
// [1024, 9216)   : cnt[128] m-tile counters, stride 16 u32 -- zeroed
// [16384,32768)  : hbuf2[2][H_] u64 {tag,val} -- zeroed (h0=0, tag=0)
// [32768,98304)  : hs[B_][H_] float (fully written by scan)
// [131072,+32MB) : xW[B_*T_][H_] float (tile-gated, no zeroing needed)

// ---- device-coherent ops (sc0 sc1 -- the ONLY transport proven to work) ----
__device__ __forceinline__ void store_u64_cohere(u64* p, u64 v) {
    asm volatile("global_store_dwordx2 %0, %1, off sc0 sc1" :: "v"(p), "v"(v) : "memory");
}
__device__ __forceinline__ void store_f32_cohere(float* p, float v) {
    asm volatile("global_store_dword %0, %1, off sc0 sc1" :: "v"(p), "v"(v) : "memory");
}
__device__ __forceinline__ u64 load_u64_cohere(const u64* p) {
    u64 r;
    asm volatile("global_load_dwordx2 %0, %1, off sc0 sc1\n\ts_waitcnt vmcnt(0)"
                 : "=v"(r) : "v"(p) : "memory");
    return r;
}
__device__ __forceinline__ u32 load_u32_cohere(const u32* p) {
    u32 r;
    asm volatile("global_load_dword %0, %1, off sc0 sc1\n\ts_waitcnt vmcnt(0)"
                 : "=v"(r) : "v"(p) : "memory");
    return r;
}
// ---- one poll packet: 2x dwordx4 (h slots 4tid..4tid+3) + this step's xW value ----
__device__ __forceinline__ void poll_h_xw(const u64* ph, const float* pxw,
                                          v4u& A, v4u& B, float& xw) {
    asm volatile(
        "global_load_dwordx4 %0, %3, off sc0 sc1\n\t"
        "global_load_dwordx4 %1, %3, off offset:16 sc0 sc1\n\t"
        "global_load_dword   %2, %4, off sc0 sc1\n\t"
        "s_waitcnt vmcnt(0)"
        : "=&v"(A), "=&v"(B), "=&v"(xw)
        : "v"(ph), "v"(pxw)
        : "memory");
}

__device__ __forceinline__ void gate_wait(unsigned target) {
    for (;;) {
        unsigned now = (unsigned)__builtin_amdgcn_s_memrealtime();
        if ((int)(now - target) >= 0) break;
        __builtin_amdgcn_s_sleep(1);
    }
}

template <int CTRL>
__device__ __forceinline__ float dpp_xadd(float v) {
    int vi = __float_as_int(v);
    int t  = __builtin_amdgcn_update_dpp(vi, vi, CTRL, 0xF, 0xF, true);
    return v + __int_as_float(t);
}

__device__ __forceinline__ float fast_tanh(float x) {
    float ax = fabsf(x);
    float e  = __expf(-2.0f * ax);
    float r  = __fdividef(1.0f - e, 1.0f + e);
    return copysignf(r, x);
}

// ---- one 64x64 GEMM tile job (baseline, unchanged) ----
__device__ __forceinline__ void gemm_tile(
    int mt, int nt, int tid,
    const float* __restrict__ x, const float* __restrict__ Wih,
    const float* __restrict__ bih, const float* __restrict__ bhh,
    float* xW, u32* cnt, float (*As)[17], float (*Bs)[17])
{
    const int tx = tid & 15, ty = tid >> 4;
    const int lrow = tid >> 2, lcol = (tid & 3) * 4;
    const float* Ag = x   + (size_t)(mt * 64 + lrow) * E_ + lcol;
    const float* Bg = Wih + (size_t)(nt * 64 + lrow) * E_ + lcol;

    float acc[4][4] = {};
    for (int kt = 0; kt < E_; kt += 16) {
        float4 av = *(const float4*)(Ag + kt);
        float4 bv = *(const float4*)(Bg + kt);
        As[lrow][lcol + 0] = av.x; As[lrow][lcol + 1] = av.y;
        As[lrow][lcol + 2] = av.z; As[lrow][lcol + 3] = av.w;
        Bs[lrow][lcol + 0] = bv.x; Bs[lrow][lcol + 1] = bv.y;
        Bs[lrow][lcol + 2] = bv.z; Bs[lrow][lcol + 3] = bv.w;
        __syncthreads();
#pragma unroll
        for (int kk = 0; kk < 16; ++kk) {
            float a0 = As[ty * 4 + 0][kk], a1 = As[ty * 4 + 1][kk];
            float a2 = As[ty * 4 + 2][kk], a3 = As[ty * 4 + 3][kk];
            float b0 = Bs[tx * 4 + 0][kk], b1 = Bs[tx * 4 + 1][kk];
            float b2 = Bs[tx * 4 + 2][kk], b3 = Bs[tx * 4 + 3][kk];
            acc[0][0] += a0 * b0; acc[0][1] += a0 * b1; acc[0][2] += a0 * b2; acc[0][3] += a0 * b3;
            acc[1][0] += a1 * b0; acc[1][1] += a1 * b1; acc[1][2] += a1 * b2; acc[1][3] += a1 * b3;
            acc[2][0] += a2 * b0; acc[2][1] += a2 * b1; acc[2][2] += a2 * b2; acc[2][3] += a2 * b3;
            acc[3][0] += a3 * b0; acc[3][1] += a3 * b1; acc[3][2] += a3 * b2; acc[3][3] += a3 * b3;
        }
        __syncthreads();
    }
#pragma unroll
    for (int i = 0; i < 4; ++i) {
        const int m = mt * 64 + ty * 4 + i;
#pragma unroll
        for (int j = 0; j < 4; ++j) {
            const int n = nt * 64 + tx * 4 + j;
            store_f32_cohere(xW + (size_t)m * H_ + n, acc[i][j] + bih[n] + bhh[n]);
        }
    }
    asm volatile("s_waitcnt vmcnt(0)" ::: "memory");  // own stores at coherence point
    __syncthreads();                                  // all threads' stores drained
    if (tid == 0) atomicAdd(cnt + mt * 16, 1u);       // device-scope publish
}

// ================= Fused kernel: WGs 0-31 scan, WGs 32-255 GEMM =================
__global__ __launch_bounds__(256, 1) void fused_scan_gemm(
    const float* __restrict__ x, const float* __restrict__ Wih,
    const float* __restrict__ bih, const float* __restrict__ bhh,
    const float* __restrict__ Whh, const int* __restrict__ lengths,
    u64* tsync, u32* cnt, u64* hbuf2, float* xW, float* hs)
{
    __shared__ float As[64][17];
    __shared__ float Bs[64][17];
    __shared__ float hsh[2][H_];
    const int tid = threadIdx.x;
    const int wg  = blockIdx.x;

    if (wg >= G_SCAN) {
        // ---------------- GEMM role: grid-stride over tile jobs, m-major ----------------
        for (int j = wg - G_SCAN; j < N_JOBS; j += (G_TOTAL - G_SCAN))
            gemm_tile(j >> 4, j & 15, tid, x, Wih, bih, bhh, xW, cnt, As, Bs);
        return;
    }

    // ---------------- scan role: 32 rows/WG, 8 lanes/row, baseline transport --------
    const int sub = tid & 7;                 // lane within row
    const int row = wg * ROWS_PER_WG + (tid >> 3);

    // W_hh fragment: wv[j] covers k = 4*sub + 32*j .. +3  (128 floats/thread)
    float4 wv[32];
#pragma unroll
    for (int j = 0; j < 32; ++j)
        wv[j] = *(const float4*)(Whh + (size_t)row * H_ + 4 * sub + 32 * j);
    // pin wv in VGPRs: prevent the rematerialize-from-global trap (r3: VGPR=76)
#pragma unroll
    for (int j = 0; j < 32; ++j)
        asm volatile("" : "+v"(wv[j].x), "+v"(wv[j].y), "+v"(wv[j].z), "+v"(wv[j].w));

    if (wg == 0 && tid == 0) {
        unsigned t0pub = (unsigned)__builtin_amdgcn_s_memrealtime() + START_DELAY;
        store_u64_cohere(tsync, ((u64)T0_MAGIC << 32) | (u64)t0pub);
    }
    unsigned t0;
    {
        u64 v;
        do { v = load_u64_cohere(tsync); } while ((unsigned)(v >> 32) != T0_MAGIC);
        t0 = (unsigned)v;
    }

    int s = 0, cur = 0, conf = -1;
    for (int b = 0; b < B_; ++b) {
        const int len = lengths[b];
        for (int t = 0; t < len; ++t) {
            const int m  = b * T_ + t;
            const int mt = m >> 6;
            if (mt > conf) {   // xW tile gate (16 n-jobs done?) -- rare: 128 total
                u32 c;
                do { c = load_u32_cohere(cnt + mt * 16); } while (c < 16u);
                conf = mt;
            }
            gate_wait(t0 + (unsigned)s * TICK_P);

            // ---- consume: poll slots 4tid..4tid+3 (2x dwordx4) + xW in one packet
            const u64*   ph  = hbuf2 + (size_t)(s & 1) * H_ + 4 * tid;
            const float* pxw = xW + (size_t)m * H_ + row;
            const u32 want = (u32)s;
            v4u A, Bv; float xw;
            for (;;) {
                poll_h_xw(ph, pxw, A, Bv, xw);
                if ((A.y == want) & (A.w == want) & (Bv.y == want) & (Bv.w == want))
                    break;
            }

            // ---- stage h into LDS (linear; reads are broadcast/conflict-free) ----
            float4 hv4;
            hv4.x = __uint_as_float(A.x);
            hv4.y = __uint_as_float(A.z);
            hv4.z = __uint_as_float(Bv.x);
            hv4.w = __uint_as_float(Bv.z);
            *(float4*)&hsh[cur][4 * tid] = hv4;
            __syncthreads();   // the per-step barrier

            // ---- matvec: row . h, k = 4*sub + 32*j + c ----
            const float* hrow = &hsh[cur][4 * sub];
            float p0 = 0.f, p1 = 0.f, p2 = 0.f, p3 = 0.f;
#pragma unroll
            for (int j = 0; j < 32; ++j) {
                float4 hv = *(const float4*)(hrow + 32 * j);
                p0 += wv[j].x * hv.x;
                p1 += wv[j].y * hv.y;
                p2 += wv[j].z * hv.z;
                p3 += wv[j].w * hv.w;
            }
            float p = (p0 + p1) + (p2 + p3);
            p = dpp_xadd<0xB1>(p);    // quad_perm xor1
            p = dpp_xadd<0x4E>(p);    // quad_perm xor2
            p = dpp_xadd<0x141>(p);   // row_half_mirror -> full 8-lane row sum

            float v = fast_tanh(xw + p);
            if (sub == 0) {
                u64 pk = ((u64)(u32)(s + 1) << 32) | (u64)__float_as_uint(v);
                store_u64_cohere(hbuf2 + (size_t)((s + 1) & 1) * H_ + row, pk);
                if (t == len - 1) hs[(size_t)b * H_ + row] = v;
            }
            cur ^= 1;
            ++s;
        }
    }
}

// ================= out = hs @ W_l1^T + b_l1  (16x128) =================
__global__ __launch_bounds__(128) void out_gemm(
    const float* __restrict__ hs, const float* __restrict__ Wl1,
    const float* __restrict__ bl1, float* __restrict__ out)
{
    __shared__ float hshared[H_];
    const int b = blockIdx.x;
    const int d = threadIdx.x;
    for (int i = d; i < H_ / 4; i += 128)
        ((float4*)hshared)[i] = ((const float4*)(hs + (size_t)b * H_))[i];
    __syncthreads();
    float acc = 0.f;
    const float* wrow = Wl1 + (size_t)d * H_;
    for (int h = 0; h < H_; h += 4) {
        float4 w = *(const float4*)(wrow + h);
        acc += w.x * hshared[h] + w.y * hshared[h + 1]
             + w.z * hshared[h + 2] + w.w * hshared[h + 3];
    }
    out[b * D_ + d] = acc + bl1[d];
}

extern "C" void kernel_launch(void* const* d_in, const int* in_sizes, int n_in,
                              void* d_out, int out_size, void* d_ws, size_t ws_size,
                              hipStream_t stream) {
    const float* x       = (const float*)d_in[0];
    const int*   lengths = (const int*)  d_in[1];
    const float* Wih     = (const float*)d_in[2];
    const float* Whh     = (const float*)d_in[3];
    const float* bih     = (const float*)d_in[4];
    const float* bhh     = (const float*)d_in[5];
    const float* Wl1     = (const float*)d_in[6];
    const float* bl1     = (const float*)d_in[7];
    float* out = (float*)d_out;

    char* ws = (char*)d_ws;
    u64*   tsync = (u64*)(ws + 256);
    u32*   cnt   = (u32*)(ws + 1024);     // 128 tiles x 16-u32 stride = 8 KB
    u64*   hbuf2 = (u64*)(ws + 16384);    // 16 KB
    float* hs    = (float*)(ws + 32768);  // 64 KB
    float* xW    = (float*)(ws + 131072); // 32 MB

    // zero tsync + cnt + hbuf2 (h0=0, tag 0); ws re-poisoned 0xAA every launch
    hipMemsetAsync(ws, 0, 32768, stream);

    fused_scan_gemm<<<G_TOTAL, 256, 0, stream>>>(
        x, Wih, bih, bhh, Whh, lengths, tsync, cnt, hbuf2, xW, hs);

    out_gemm<<<B_, D_, 0, stream>>>(hs, Wl1, bl1, out);
}

// Round 6
// 7500.349 us; speedup vs baseline: 2.2727x; 1.1451x over previous
//
#include <hip/hip_runtime.h>
#include <math.h>

#define B_ 16
#define T_ 512
#define E_ 2048
#define H_ 1024
#define D_ 128
#define G_SCAN 64            // scan WGs (baseline-proven; r5 showed 32 is worse)
#define ROWS_PER_WG 16       // H_/G_SCAN
#define G_TOTAL 256          // scan + gemm WGs, all co-resident (1 block/CU)
#define N_JOBS 2048          // 128 m-tiles x 16 n-tiles
#define TICK_P 75            // per-step gate (baseline-measured best)
#define START_DELAY 2000
#define T0_MAGIC 0x7F7F7F7Fu

typedef unsigned long long u64;
typedef unsigned int u32;
typedef __attribute__((ext_vector_type(4))) u32 v4u;

// ---------------- ws layout ----------------
// [256,  264)    : T0 handshake slot (u64 {magic,t0}) -- zeroed each launch
// [1024, 9216)   : cnt[128] m-tile counters, stride 16 u32 -- zeroed
// [16384,32768)  : hbuf2[2][H_] u64 {tag,val} -- zeroed (h0=0, tag=0)
// [32768,98304)  : hs[B_][H_] float (fully written by scan)
// [131072,+32MB) : xW[B_*T_][H_] float (tile-gated, no zeroing needed)

// ---- device-coherent ops (sc0 sc1 -- the ONLY transport proven to work;
//      r3: sc0-only polls never see remote stores; r4: sc1-only stores hang) ----
__device__ __forceinline__ void store_u64_cohere(u64* p, u64 v) {
    asm volatile("global_store_dwordx2 %0, %1, off sc0 sc1" :: "v"(p), "v"(v) : "memory");
}
__device__ __forceinline__ void store_f32_cohere(float* p, float v) {
    asm volatile("global_store_dword %0, %1, off sc0 sc1" :: "v"(p), "v"(v) : "memory");
}
__device__ __forceinline__ u64 load_u64_cohere(const u64* p) {
    u64 r;
    asm volatile("global_load_dwordx2 %0, %1, off sc0 sc1\n\ts_waitcnt vmcnt(0)"
                 : "=v"(r) : "v"(p) : "memory");
    return r;
}
__device__ __forceinline__ u32 load_u32_cohere(const u32* p) {
    u32 r;
    asm volatile("global_load_dword %0, %1, off sc0 sc1\n\ts_waitcnt vmcnt(0)"
                 : "=v"(r) : "v"(p) : "memory");
    return r;
}
// ---- one poll packet: 2x dwordx4 (h slots 4tid..4tid+3) + this step's xW value ----
__device__ __forceinline__ void poll_h_xw(const u64* ph, const float* pxw,
                                          v4u& A, v4u& B, float& xw) {
    asm volatile(
        "global_load_dwordx4 %0, %3, off sc0 sc1\n\t"
        "global_load_dwordx4 %1, %3, off offset:16 sc0 sc1\n\t"
        "global_load_dword   %2, %4, off sc0 sc1\n\t"
        "s_waitcnt vmcnt(0)"
        : "=&v"(A), "=&v"(B), "=&v"(xw)
        : "v"(ph), "v"(pxw)
        : "memory");
}

__device__ __forceinline__ void gate_wait(unsigned target) {
    for (;;) {
        unsigned now = (unsigned)__builtin_amdgcn_s_memrealtime();
        if ((int)(now - target) >= 0) break;
        __builtin_amdgcn_s_sleep(1);
    }
}

template <int CTRL>
__device__ __forceinline__ float dpp_xadd(float v) {
    int vi = __float_as_int(v);
    int t  = __builtin_amdgcn_update_dpp(vi, vi, CTRL, 0xF, 0xF, true);
    return v + __int_as_float(t);
}

__device__ __forceinline__ float fast_tanh(float x) {
    float ax = fabsf(x);
    float e  = __expf(-2.0f * ax);
    float r  = __fdividef(1.0f - e, 1.0f + e);
    return copysignf(r, x);
}

// ---- one 64x64 GEMM tile job (baseline, unchanged) ----
__device__ __forceinline__ void gemm_tile(
    int mt, int nt, int tid,
    const float* __restrict__ x, const float* __restrict__ Wih,
    const float* __restrict__ bih, const float* __restrict__ bhh,
    float* xW, u32* cnt, float (*As)[17], float (*Bs)[17])
{
    const int tx = tid & 15, ty = tid >> 4;
    const int lrow = tid >> 2, lcol = (tid & 3) * 4;
    const float* Ag = x   + (size_t)(mt * 64 + lrow) * E_ + lcol;
    const float* Bg = Wih + (size_t)(nt * 64 + lrow) * E_ + lcol;

    float acc[4][4] = {};
    for (int kt = 0; kt < E_; kt += 16) {
        float4 av = *(const float4*)(Ag + kt);
        float4 bv = *(const float4*)(Bg + kt);
        As[lrow][lcol + 0] = av.x; As[lrow][lcol + 1] = av.y;
        As[lrow][lcol + 2] = av.z; As[lrow][lcol + 3] = av.w;
        Bs[lrow][lcol + 0] = bv.x; Bs[lrow][lcol + 1] = bv.y;
        Bs[lrow][lcol + 2] = bv.z; Bs[lrow][lcol + 3] = bv.w;
        __syncthreads();
#pragma unroll
        for (int kk = 0; kk < 16; ++kk) {
            float a0 = As[ty * 4 + 0][kk], a1 = As[ty * 4 + 1][kk];
            float a2 = As[ty * 4 + 2][kk], a3 = As[ty * 4 + 3][kk];
            float b0 = Bs[tx * 4 + 0][kk], b1 = Bs[tx * 4 + 1][kk];
            float b2 = Bs[tx * 4 + 2][kk], b3 = Bs[tx * 4 + 3][kk];
            acc[0][0] += a0 * b0; acc[0][1] += a0 * b1; acc[0][2] += a0 * b2; acc[0][3] += a0 * b3;
            acc[1][0] += a1 * b0; acc[1][1] += a1 * b1; acc[1][2] += a1 * b2; acc[1][3] += a1 * b3;
            acc[2][0] += a2 * b0; acc[2][1] += a2 * b1; acc[2][2] += a2 * b2; acc[2][3] += a2 * b3;
            acc[3][0] += a3 * b0; acc[3][1] += a3 * b1; acc[3][2] += a3 * b2; acc[3][3] += a3 * b3;
        }
        __syncthreads();
    }
#pragma unroll
    for (int i = 0; i < 4; ++i) {
        const int m = mt * 64 + ty * 4 + i;
#pragma unroll
        for (int j = 0; j < 4; ++j) {
            const int n = nt * 64 + tx * 4 + j;
            store_f32_cohere(xW + (size_t)m * H_ + n, acc[i][j] + bih[n] + bhh[n]);
        }
    }
    asm volatile("s_waitcnt vmcnt(0)" ::: "memory");  // own stores at coherence point
    __syncthreads();                                  // all threads' stores drained
    if (tid == 0) atomicAdd(cnt + mt * 16, 1u);       // device-scope publish
}

// ================= Fused kernel: WGs 0-63 scan, WGs 64-255 GEMM =================
// waves_per_eu(1,1): truthful (1 block/CU x 4 waves = 1/EU) -> raises regalloc
// budget so the scan's 64 W-floats/thread stay VGPR-resident (r5: spill trap).
__global__ __launch_bounds__(256)
__attribute__((amdgpu_waves_per_eu(1, 1)))
void fused_scan_gemm(
    const float* __restrict__ x, const float* __restrict__ Wih,
    const float* __restrict__ bih, const float* __restrict__ bhh,
    const float* __restrict__ Whh, const int* __restrict__ lengths,
    u64* tsync, u32* cnt, u64* hbuf2, float* xW, float* hs)
{
    __shared__ float As[64][17];
    __shared__ float Bs[64][17];
    __shared__ float hsh[2][H_];
    const int tid = threadIdx.x;
    const int wg  = blockIdx.x;

    if (wg >= G_SCAN) {
        // ---------------- GEMM role: grid-stride over tile jobs, m-major ----------------
        for (int j = wg - G_SCAN; j < N_JOBS; j += (G_TOTAL - G_SCAN))
            gemm_tile(j >> 4, j & 15, tid, x, Wih, bih, bhh, xW, cnt, As, Bs);
        return;
    }

    // ---------------- scan role: 16 rows/WG, 16 lanes/row, contiguous-k W frags ----
    const int r   = tid >> 4;
    const int sub = tid & 15;
    const int row = wg * ROWS_PER_WG + r;

    // W_hh fragment: wv[j] covers k = 4*sub + 64*j .. +3  (64 floats/thread)
    float4 wv[16];
#pragma unroll
    for (int j = 0; j < 16; ++j)
        wv[j] = *(const float4*)(Whh + (size_t)row * H_ + 4 * sub + 64 * j);
    // pin in VGPRs (with waves_per_eu(1,1) budget the compiler can honor this)
#pragma unroll
    for (int j = 0; j < 16; ++j)
        asm volatile("" : "+v"(wv[j].x), "+v"(wv[j].y), "+v"(wv[j].z), "+v"(wv[j].w));

    if (wg == 0 && tid == 0) {
        unsigned t0pub = (unsigned)__builtin_amdgcn_s_memrealtime() + START_DELAY;
        store_u64_cohere(tsync, ((u64)T0_MAGIC << 32) | (u64)t0pub);
    }
    unsigned t0;
    {
        u64 v;
        do { v = load_u64_cohere(tsync); } while ((unsigned)(v >> 32) != T0_MAGIC);
        t0 = (unsigned)v;
    }

    int s = 0, cur = 0, conf = -1;
    for (int b = 0; b < B_; ++b) {
        const int len = lengths[b];
        for (int t = 0; t < len; ++t) {
            const int m  = b * T_ + t;
            const int mt = m >> 6;
            if (mt > conf) {   // xW tile gate (16 n-jobs done?) -- rare: 128 total
                u32 c;
                do { c = load_u32_cohere(cnt + mt * 16); } while (c < 16u);
                conf = mt;
            }
            gate_wait(t0 + (unsigned)s * TICK_P);

            // ---- consume: poll slots 4tid..4tid+3 (2x dwordx4) + xW in one packet
            const u64*   ph  = hbuf2 + (size_t)(s & 1) * H_ + 4 * tid;
            const float* pxw = xW + (size_t)m * H_ + row;
            const u32 want = (u32)s;
            v4u A, Bv; float xw;
            for (;;) {
                poll_h_xw(ph, pxw, A, Bv, xw);
                if ((A.y == want) & (A.w == want) & (Bv.y == want) & (Bv.w == want))
                    break;
            }

            // ---- stage h into LDS: linear layout, one float4 write ----
            float4 hv4;
            hv4.x = __uint_as_float(A.x);
            hv4.y = __uint_as_float(A.z);
            hv4.z = __uint_as_float(Bv.x);
            hv4.w = __uint_as_float(Bv.z);
            *(float4*)&hsh[cur][4 * tid] = hv4;
            __syncthreads();   // the per-step barrier

            // ---- matvec: row . h, k = 4*sub + 64*j + c (broadcast LDS reads) ----
            const float* hrow = &hsh[cur][4 * sub];
            float p0 = 0.f, p1 = 0.f, p2 = 0.f, p3 = 0.f;
#pragma unroll
            for (int j = 0; j < 16; ++j) {
                float4 hv = *(const float4*)(hrow + 64 * j);
                p0 += wv[j].x * hv.x;
                p1 += wv[j].y * hv.y;
                p2 += wv[j].z * hv.z;
                p3 += wv[j].w * hv.w;
            }
            float p = (p0 + p1) + (p2 + p3);
            p = dpp_xadd<0xB1>(p);    // quad_perm xor1
            p = dpp_xadd<0x4E>(p);    // quad_perm xor2
            p = dpp_xadd<0x141>(p);   // row_half_mirror
            p = dpp_xadd<0x140>(p);   // row_mirror -> full 16-lane row sum

            float v = fast_tanh(xw + p);
            if (sub == 0) {
                u64 pk = ((u64)(u32)(s + 1) << 32) | (u64)__float_as_uint(v);
                store_u64_cohere(hbuf2 + (size_t)((s + 1) & 1) * H_ + row, pk);
                if (t == len - 1) hs[(size_t)b * H_ + row] = v;
            }
            cur ^= 1;
            ++s;
        }
    }
}

// ================= out = hs @ W_l1^T + b_l1  (16x128) =================
__global__ __launch_bounds__(128) void out_gemm(
    const float* __restrict__ hs, const float* __restrict__ Wl1,
    const float* __restrict__ bl1, float* __restrict__ out)
{
    __shared__ float hshared[H_];
    const int b = blockIdx.x;
    const int d = threadIdx.x;
    for (int i = d; i < H_ / 4; i += 128)
        ((float4*)hshared)[i] = ((const float4*)(hs + (size_t)b * H_))[i];
    __syncthreads();
    float acc = 0.f;
    const float* wrow = Wl1 + (size_t)d * H_;
    for (int h = 0; h < H_; h += 4) {
        float4 w = *(const float4*)(wrow + h);
        acc += w.x * hshared[h] + w.y * hshared[h + 1]
             + w.z * hshared[h + 2] + w.w * hshared[h + 3];
    }
    out[b * D_ + d] = acc + bl1[d];
}

extern "C" void kernel_launch(void* const* d_in, const int* in_sizes, int n_in,
                              void* d_out, int out_size, void* d_ws, size_t ws_size,
                              hipStream_t stream) {
    const float* x       = (const float*)d_in[0];
    const int*   lengths = (const int*)  d_in[1];
    const float* Wih     = (const float*)d_in[2];
    const float* Whh     = (const float*)d_in[3];
    const float* bih     = (const float*)d_in[4];
    const float* bhh     = (const float*)d_in[5];
    const float* Wl1     = (const float*)d_in[6];
    const float* bl1     = (const float*)d_in[7];
    float* out = (float*)d_out;

    char* ws = (char*)d_ws;
    u64*   tsync = (u64*)(ws + 256);
    u32*   cnt   = (u32*)(ws + 1024);     // 128 tiles x 16-u32 stride = 8 KB
    u64*   hbuf2 = (u64*)(ws + 16384);    // 16 KB
    float* hs    = (float*)(ws + 32768);  // 64 KB
    float* xW    = (float*)(ws + 131072); // 32 MB

    // zero tsync + cnt + hbuf2 (h0=0, tag 0); ws re-poisoned 0xAA every launch
    hipMemsetAsync(ws, 0, 32768, stream);

    fused_scan_gemm<<<G_TOTAL, 256, 0, stream>>>(
        x, Wih, bih, bhh, Whh, lengths, tsync, cnt, hbuf2, xW, hs);

    out_gemm<<<B_, D_, 0, stream>>>(hs, Wl1, bl1, out);
}

// Round 8
// 7168.942 us; speedup vs baseline: 2.3778x; 1.0462x over previous
//
#include <hip/hip_runtime.h>
#include <math.h>

#define B_ 16
#define T_ 512
#define E_ 2048
#define H_ 1024
#define D_ 128
#define G_SCAN 64            // scan WGs (1 per CU)
#define ROWS_PER_WG 16       // H_/G_SCAN
#define G_TOTAL 256          // scan + gemm WGs, all co-resident (capacity >= 2 blocks/CU)
#define N_JOBS 2048          // 128 m-tiles x 16 n-tiles
#define TICK_P 75            // vestigial per-step gate (r7-measured best)
#define START_DELAY 2000
#define T0_MAGIC 0x7F7F7F7Fu

typedef unsigned long long u64;
typedef unsigned int u32;
typedef __attribute__((ext_vector_type(4))) u32 v4u;

// ---------------- ws layout ----------------
// [256,  264)    : T0 handshake slot (u64 {magic,t0}) -- zeroed each launch
// [1024, 9216)   : cnt[128] m-tile counters, stride 16 u32 (64B/line) -- zeroed
// [16384,32768)  : hbuf2[2][H_] u64 {tag,val} -- zeroed (h0=0, tag=0)
// [32768,98304)  : hs[B_][H_] float (fully written by scan)
// [131072,+32MB) : xW[B_*T_][H_] float (tile-gated, no zeroing needed)

// ---- device-coherent ops (sc0 sc1 -> coherence point; stores write through) ----
__device__ __forceinline__ void store_u64_cohere(u64* p, u64 v) {
    asm volatile("global_store_dwordx2 %0, %1, off sc0 sc1" :: "v"(p), "v"(v) : "memory");
}
__device__ __forceinline__ void store_f32_cohere(float* p, float v) {
    asm volatile("global_store_dword %0, %1, off sc0 sc1" :: "v"(p), "v"(v) : "memory");
}
__device__ __forceinline__ u64 load_u64_cohere(const u64* p) {
    u64 r;
    asm volatile("global_load_dwordx2 %0, %1, off sc0 sc1\n\ts_waitcnt vmcnt(0)"
                 : "=v"(r) : "v"(p) : "memory");
    return r;
}
__device__ __forceinline__ u32 load_u32_cohere(const u32* p) {
    u32 r;
    asm volatile("global_load_dword %0, %1, off sc0 sc1\n\ts_waitcnt vmcnt(0)"
                 : "=v"(r) : "v"(p) : "memory");
    return r;
}
// ---- one poll packet: 2x dwordx4 (h slots 4tid..4tid+3) + this step's xW value ----
__device__ __forceinline__ void poll_h_xw(const u64* ph, const float* pxw,
                                          v4u& A, v4u& B, float& xw) {
    asm volatile(
        "global_load_dwordx4 %0, %3, off sc0 sc1\n\t"
        "global_load_dwordx4 %1, %3, off offset:16 sc0 sc1\n\t"
        "global_load_dword   %2, %4, off sc0 sc1\n\t"
        "s_waitcnt vmcnt(0)"
        : "=&v"(A), "=&v"(B), "=&v"(xw)
        : "v"(ph), "v"(pxw)
        : "memory");
}

__device__ __forceinline__ void gate_wait(unsigned target) {
    for (;;) {
        unsigned now = (unsigned)__builtin_amdgcn_s_memrealtime();
        if ((int)(now - target) >= 0) break;
        __builtin_amdgcn_s_sleep(1);
    }
}

template <int CTRL>
__device__ __forceinline__ float dpp_xadd(float v) {
    int vi = __float_as_int(v);
    int t  = __builtin_amdgcn_update_dpp(vi, vi, CTRL, 0xF, 0xF, true);
    return v + __int_as_float(t);
}

__device__ __forceinline__ float fast_tanh(float x) {
    float ax = fabsf(x);
    float e  = __expf(-2.0f * ax);
    float r  = __fdividef(1.0f - e, 1.0f + e);
    return copysignf(r, x);
}

// ---- one 64x64 GEMM tile job: xW[mt-tile][nt-tile], write-through + counter ----
__device__ __forceinline__ void gemm_tile(
    int mt, int nt, int tid,
    const float* __restrict__ x, const float* __restrict__ Wih,
    const float* __restrict__ bih, const float* __restrict__ bhh,
    float* xW, u32* cnt, float (*As)[17], float (*Bs)[17])
{
    const int tx = tid & 15, ty = tid >> 4;
    const int lrow = tid >> 2, lcol = (tid & 3) * 4;
    const float* Ag = x   + (size_t)(mt * 64 + lrow) * E_ + lcol;
    const float* Bg = Wih + (size_t)(nt * 64 + lrow) * E_ + lcol;

    float acc[4][4] = {};
    for (int kt = 0; kt < E_; kt += 16) {
        float4 av = *(const float4*)(Ag + kt);
        float4 bv = *(const float4*)(Bg + kt);
        As[lrow][lcol + 0] = av.x; As[lrow][lcol + 1] = av.y;
        As[lrow][lcol + 2] = av.z; As[lrow][lcol + 3] = av.w;
        Bs[lrow][lcol + 0] = bv.x; Bs[lrow][lcol + 1] = bv.y;
        Bs[lrow][lcol + 2] = bv.z; Bs[lrow][lcol + 3] = bv.w;
        __syncthreads();
#pragma unroll
        for (int kk = 0; kk < 16; ++kk) {
            float a0 = As[ty * 4 + 0][kk], a1 = As[ty * 4 + 1][kk];
            float a2 = As[ty * 4 + 2][kk], a3 = As[ty * 4 + 3][kk];
            float b0 = Bs[tx * 4 + 0][kk], b1 = Bs[tx * 4 + 1][kk];
            float b2 = Bs[tx * 4 + 2][kk], b3 = Bs[tx * 4 + 3][kk];
            acc[0][0] += a0 * b0; acc[0][1] += a0 * b1; acc[0][2] += a0 * b2; acc[0][3] += a0 * b3;
            acc[1][0] += a1 * b0; acc[1][1] += a1 * b1; acc[1][2] += a1 * b2; acc[1][3] += a1 * b3;
            acc[2][0] += a2 * b0; acc[2][1] += a2 * b1; acc[2][2] += a2 * b2; acc[2][3] += a2 * b3;
            acc[3][0] += a3 * b0; acc[3][1] += a3 * b1; acc[3][2] += a3 * b2; acc[3][3] += a3 * b3;
        }
        __syncthreads();
    }
#pragma unroll
    for (int i = 0; i < 4; ++i) {
        const int m = mt * 64 + ty * 4 + i;
#pragma unroll
        for (int j = 0; j < 4; ++j) {
            const int n = nt * 64 + tx * 4 + j;
            store_f32_cohere(xW + (size_t)m * H_ + n, acc[i][j] + bih[n] + bhh[n]);
        }
    }
    asm volatile("s_waitcnt vmcnt(0)" ::: "memory");  // own stores at coherence point
    __syncthreads();                                  // all threads' stores drained
    if (tid == 0) atomicAdd(cnt + mt * 16, 1u);       // device-scope publish
}

// ================= Fused kernel: WGs 0-63 scan, WGs 64-255 GEMM =================
__global__ __launch_bounds__(256, 1) void fused_scan_gemm(
    const float* __restrict__ x, const float* __restrict__ Wih,
    const float* __restrict__ bih, const float* __restrict__ bhh,
    const float* __restrict__ Whh, const int* __restrict__ lengths,
    u64* tsync, u32* cnt, u64* hbuf2, float* xW, float* hs)
{
    __shared__ float As[64][17];
    __shared__ float Bs[64][17];
    __shared__ float hsh2[2][16 * 68];
    const int tid = threadIdx.x;
    const int wg  = blockIdx.x;

    if (wg >= G_SCAN) {
        // ---------------- GEMM role: grid-stride over tile jobs, m-major ----------------
        for (int j = wg - G_SCAN; j < N_JOBS; j += (G_TOTAL - G_SCAN))
            gemm_tile(j >> 4, j & 15, tid, x, Wih, bih, bhh, xW, cnt, As, Bs);
        return;
    }

    // ---------------- scan role (round-7 transport, dwordx4 polls) ----------------
    const int r   = tid >> 4;
    const int sub = tid & 15;
    const int row = wg * ROWS_PER_WG + r;

    float wreg[64];
#pragma unroll
    for (int j = 0; j < 64; ++j)
        wreg[j] = Whh[(size_t)row * H_ + sub + 16 * j];

    // slot c = 4*tid+k lives at hsh2[cur][(c&15)*68 + (c>>4)] = stage_base + 68k
    const int stage_base = 4 * (tid & 3) * 68 + (tid >> 2);

    if (wg == 0 && tid == 0) {
        unsigned t0pub = (unsigned)__builtin_amdgcn_s_memrealtime() + START_DELAY;
        store_u64_cohere(tsync, ((u64)T0_MAGIC << 32) | (u64)t0pub);
    }
    unsigned t0;
    {
        u64 v;
        do { v = load_u64_cohere(tsync); } while ((unsigned)(v >> 32) != T0_MAGIC);
        t0 = (unsigned)v;
    }

    int s = 0, cur = 0, conf = -1;
    for (int b = 0; b < B_; ++b) {
        const int len = lengths[b];
        for (int t = 0; t < len; ++t) {
            const int m  = b * T_ + t;
            const int mt = m >> 6;
            if (mt > conf) {   // xW tile gate (16 n-jobs done?) -- rare: 128 total
                u32 c;
                do { c = load_u32_cohere(cnt + mt * 16); } while (c < 16u);
                conf = mt;
            }
            gate_wait(t0 + (unsigned)s * TICK_P);

            // ---- consume: poll slots 4tid..4tid+3 (2x dwordx4) + xW in one packet
            const u64*   ph  = hbuf2 + (size_t)(s & 1) * H_ + 4 * tid;
            const float* pxw = xW + (size_t)m * H_ + row;
            const u32 want = (u32)s;
            v4u A, Bv; float xw;
            for (;;) {
                poll_h_xw(ph, pxw, A, Bv, xw);
                if ((A.y == want) & (A.w == want) & (Bv.y == want) & (Bv.w == want))
                    break;
            }

            float* wrp = &hsh2[cur][stage_base];
            wrp[0]   = __uint_as_float(A.x);
            wrp[68]  = __uint_as_float(A.z);
            wrp[136] = __uint_as_float(Bv.x);
            wrp[204] = __uint_as_float(Bv.z);
            __syncthreads();   // the per-step barrier

            const float* hrow = &hsh2[cur][sub * 68];
            float p0 = 0.f, p1 = 0.f, p2 = 0.f, p3 = 0.f;
#pragma unroll
            for (int mm = 0; mm < 16; ++mm) {
                float4 hv = *(const float4*)(hrow + 4 * mm);
                p0 += wreg[4 * mm + 0] * hv.x;
                p1 += wreg[4 * mm + 1] * hv.y;
                p2 += wreg[4 * mm + 2] * hv.z;
                p3 += wreg[4 * mm + 3] * hv.w;
            }
            float p = (p0 + p1) + (p2 + p3);
            p = dpp_xadd<0xB1>(p);    // quad_perm xor1
            p = dpp_xadd<0x4E>(p);    // quad_perm xor2
            p = dpp_xadd<0x141>(p);   // row_half_mirror
            p = dpp_xadd<0x140>(p);   // row_mirror

            float v = fast_tanh(xw + p);
            if (sub == 0) {
                u64 pk = ((u64)(u32)(s + 1) << 32) | (u64)__float_as_uint(v);
                store_u64_cohere(hbuf2 + (size_t)((s + 1) & 1) * H_ + row, pk);
                if (t == len - 1) hs[(size_t)b * H_ + row] = v;
            }
            cur ^= 1;
            ++s;
        }
    }
}

// ================= out = hs @ W_l1^T + b_l1  (16x128) =================
__global__ __launch_bounds__(128) void out_gemm(
    const float* __restrict__ hs, const float* __restrict__ Wl1,
    const float* __restrict__ bl1, float* __restrict__ out)
{
    __shared__ float hshared[H_];
    const int b = blockIdx.x;
    const int d = threadIdx.x;
    for (int i = d; i < H_ / 4; i += 128)
        ((float4*)hshared)[i] = ((const float4*)(hs + (size_t)b * H_))[i];
    __syncthreads();
    float acc = 0.f;
    const float* wrow = Wl1 + (size_t)d * H_;
    for (int h = 0; h < H_; h += 4) {
        float4 w = *(const float4*)(wrow + h);
        acc += w.x * hshared[h] + w.y * hshared[h + 1]
             + w.z * hshared[h + 2] + w.w * hshared[h + 3];
    }
    out[b * D_ + d] = acc + bl1[d];
}

extern "C" void kernel_launch(void* const* d_in, const int* in_sizes, int n_in,
                              void* d_out, int out_size, void* d_ws, size_t ws_size,
                              hipStream_t stream) {
    const float* x       = (const float*)d_in[0];
    const int*   lengths = (const int*)  d_in[1];
    const float* Wih     = (const float*)d_in[2];
    const float* Whh     = (const float*)d_in[3];
    const float* bih     = (const float*)d_in[4];
    const float* bhh     = (const float*)d_in[5];
    const float* Wl1     = (const float*)d_in[6];
    const float* bl1     = (const float*)d_in[7];
    float* out = (float*)d_out;

    char* ws = (char*)d_ws;
    u64*   tsync = (u64*)(ws + 256);
    u32*   cnt   = (u32*)(ws + 1024);     // 128 tiles x 16-u32 stride = 8 KB
    u64*   hbuf2 = (u64*)(ws + 16384);    // 16 KB
    float* hs    = (float*)(ws + 32768);  // 64 KB
    float* xW    = (float*)(ws + 131072); // 32 MB

    // zero tsync + cnt + hbuf2 (h0=0, tag 0); ws re-poisoned 0xAA every launch
    hipMemsetAsync(ws, 0, 32768, stream);

    fused_scan_gemm<<<G_TOTAL, 256, 0, stream>>>(
        x, Wih, bih, bhh, Whh, lengths, tsync, cnt, hbuf2, xW, hs);

    out_gemm<<<B_, D_, 0, stream>>>(hs, Wl1, bl1, out);
}